// Round 1
// baseline (240.177 us; speedup 1.0000x reference)
//
#include <hip/hip_runtime.h>
#include <stdint.h>

// WaveletLayer fused kernel (fp32): db2 DWT (symmetric ext) -> scale cD by
// weight[0] -> db2 IDWT -> leaky_relu(0.01).
//
// R3 structure: one WAVE = one row of N=512. Lane t owns 8 consecutive
// floats x[8t..8t+7] (two float4 loads). The 2-float halo on each side is
// wave-internal -> 4 __shfl ops; NO LDS, NO __syncthreads. Lane->column
// mapping is fixed across rows, so the 5 per-lane weights are loaded into
// registers once and reused across a grid-stride loop over rows.
// 2048 blocks x 256 thr (4 waves = 4 rows/iter) = 8 blocks/CU, 32 waves/CU.
//
// Index algebra (identical to the harness-verified R2 kernel):
//   cA[i] = DL3*x[2i-2] + DL2*x[2i-1] + DL1*x[2i] + DL0*x[2i+1]  (interior)
//   i=0: taps (x1,x0,x0,x1)   i=256: taps (x510,x511,x511,x510)
//   even j: z = RL2*A[i] + RL0*A[i+1] + RH2*D[i] + RH0*D[i+1],  i=j/2
//   odd  j: z = RL3*A[i] + RL1*A[i+1] + RH3*D[i] + RH1*D[i+1]
//   with D = weight[0] * cD.
// Lane t computes pairs i = 4t..4t+4 (A0..A4/D0..D4) and outputs j=8t..8t+7.
// Boundary reflections collapse to own-register substitutions at lane 0/63.

#define N 512

typedef float f4v __attribute__((ext_vector_type(4)));

__global__ __launch_bounds__(256) void wavelet_kernel(
    const float* __restrict__ x,
    const float* __restrict__ w,
    float* __restrict__ out,
    int nrows)
{
    constexpr float DL0 = -0.12940952255092145f, DL1 = 0.22414386804185735f,
                    DL2 =  0.836516303737469f,   DL3 = 0.48296291314469025f;
    constexpr float DH0 = -0.48296291314469025f, DH1 = 0.836516303737469f,
                    DH2 = -0.22414386804185735f, DH3 = -0.12940952255092145f;
    constexpr float RL0 =  0.48296291314469025f, RL1 = 0.836516303737469f,
                    RL2 =  0.22414386804185735f, RL3 = -0.12940952255092145f;
    constexpr float RH0 = -0.12940952255092145f, RH1 = -0.22414386804185735f,
                    RH2 =  0.836516303737469f,   RH3 = -0.48296291314469025f;

    const int lane = threadIdx.x & 63;
    const int wid  = threadIdx.x >> 6;

    // Per-lane weights: lane t scales pairs i = 4t .. 4t+4. Fixed across
    // rows -> registers, loaded once. w[4t..4t+3] is 16B-aligned.
    const f4v  wv = *(const f4v*)(w + 4 * lane);
    const float w4 = w[4 * lane + 4];

    const int rstep = (int)gridDim.x * 4;

    for (int row = (int)blockIdx.x * 4 + wid; row < nrows; row += rstep) {
        const size_t base = (size_t)row * N + ((size_t)lane << 3);
        f4v va = *(const f4v*)(x + base);       // x[8t .. 8t+3]
        f4v vb = *(const f4v*)(x + base + 4);   // x[8t+4 .. 8t+7]

        // wave-internal halo: lane t-1's e6,e7 and lane t+1's e0,e1
        float xl0 = __shfl_up(vb.z, 1);         // x[8t-2]
        float xl1 = __shfl_up(vb.w, 1);         // x[8t-1]
        float xr0 = __shfl_down(va.x, 1);       // x[8t+8]
        float xr1 = __shfl_down(va.y, 1);       // x[8t+9]
        // symmetric-extension reflections (verified own-register substitutions)
        if (lane == 0)  { xl0 = va.y; xl1 = va.x; }   // i=0 taps (x1,x0,x0,x1)
        if (lane == 63) { xr0 = vb.w; xr1 = vb.z; }   // i=256 taps (x510,x511,x511,x510)

        // five coefficient pairs: i = 4t+k, k=0..4
        float A0 = DL3*xl0  + DL2*xl1  + DL1*va.x + DL0*va.y;
        float D0 = DH3*xl0  + DH2*xl1  + DH1*va.x + DH0*va.y;
        float A1 = DL3*va.x + DL2*va.y + DL1*va.z + DL0*va.w;
        float D1 = DH3*va.x + DH2*va.y + DH1*va.z + DH0*va.w;
        float A2 = DL3*va.z + DL2*va.w + DL1*vb.x + DL0*vb.y;
        float D2 = DH3*va.z + DH2*va.w + DH1*vb.x + DH0*vb.y;
        float A3 = DL3*vb.x + DL2*vb.y + DL1*vb.z + DL0*vb.w;
        float D3 = DH3*vb.x + DH2*vb.y + DH1*vb.z + DH0*vb.w;
        float A4 = DL3*vb.z + DL2*vb.w + DL1*xr0  + DL0*xr1;
        float D4 = DH3*vb.z + DH2*vb.w + DH1*xr0  + DH0*xr1;

        D0 *= wv.x; D1 *= wv.y; D2 *= wv.z; D3 *= wv.w; D4 *= w4;

        // IDWT: 8 consecutive outputs j = 8t .. 8t+7
        float z0 = RL2*A0 + RL0*A1 + RH2*D0 + RH0*D1;
        float z1 = RL3*A0 + RL1*A1 + RH3*D0 + RH1*D1;
        float z2 = RL2*A1 + RL0*A2 + RH2*D1 + RH0*D2;
        float z3 = RL3*A1 + RL1*A2 + RH3*D1 + RH1*D2;
        float z4 = RL2*A2 + RL0*A3 + RH2*D2 + RH0*D3;
        float z5 = RL3*A2 + RL1*A3 + RH3*D2 + RH1*D3;
        float z6 = RL2*A3 + RL0*A4 + RH2*D3 + RH0*D4;
        float z7 = RL3*A3 + RL1*A4 + RH3*D3 + RH1*D4;

        // leaky_relu(0.01): max(z,0) + 0.01*min(z,0)
        f4v oa, ob;
        oa.x = fmaxf(z0, 0.f) + 0.01f * fminf(z0, 0.f);
        oa.y = fmaxf(z1, 0.f) + 0.01f * fminf(z1, 0.f);
        oa.z = fmaxf(z2, 0.f) + 0.01f * fminf(z2, 0.f);
        oa.w = fmaxf(z3, 0.f) + 0.01f * fminf(z3, 0.f);
        ob.x = fmaxf(z4, 0.f) + 0.01f * fminf(z4, 0.f);
        ob.y = fmaxf(z5, 0.f) + 0.01f * fminf(z5, 0.f);
        ob.z = fmaxf(z6, 0.f) + 0.01f * fminf(z6, 0.f);
        ob.w = fmaxf(z7, 0.f) + 0.01f * fminf(z7, 0.f);

        // NT stores: output is never re-read; don't evict L3-resident input.
        __builtin_nontemporal_store(oa, (f4v*)(out + base));
        __builtin_nontemporal_store(ob, (f4v*)(out + base + 4));
    }
}

extern "C" void kernel_launch(void* const* d_in, const int* in_sizes, int n_in,
                              void* d_out, int out_size, void* d_ws, size_t ws_size,
                              hipStream_t stream) {
    const float* x = (const float*)d_in[0];
    const float* w = (const float*)d_in[1];
    float* out = (float*)d_out;

    const int nrows = in_sizes[0] / N;          // in_sizes is element count
    int blocks = (nrows + 3) / 4;               // 4 rows per block-iteration
    if (blocks > 2048) blocks = 2048;           // 8 blocks/CU, grid-stride rest
    if (blocks < 1) blocks = 1;
    wavelet_kernel<<<blocks, 256, 0, stream>>>(x, w, out, nrows);
}

// Round 2
// 232.382 us; speedup vs baseline: 1.0335x; 1.0335x over previous
//
#include <hip/hip_runtime.h>
#include <stdint.h>

// WaveletLayer fused kernel (fp32): db2 DWT (symmetric ext) -> scale cD by
// weight[0] -> db2 IDWT -> leaky_relu(0.01).
//
// R4 structure: one WAVE = TWO rows of N=512 per loop iteration. Lane t owns
// 8 consecutive floats of each row (two float4 loads/row). All 4 loads are
// issued before any use -> 64 B/lane in flight (2x the MLP of R3, which was
// register-starved at VGPR_Count=28 and plateaued at 50% of copy BW).
// Halo (2 floats each side) via 4 __shfl per row; no LDS, no barrier.
// Stores are PLAIN (R3's nontemporal stores pinned the write stream at
// 1.76 TB/s; cached stores drain through L2 at copy rate).
// Per-lane weights live in registers, reused across the grid-stride loop.
// 2048 blocks x 256 thr = 8 blocks/CU, 32 waves/CU; 4 pair-iterations/wave.
//
// Index algebra (harness-verified in R2/R3):
//   cA[i] = DL3*x[2i-2] + DL2*x[2i-1] + DL1*x[2i] + DL0*x[2i+1]  (interior)
//   i=0: taps (x1,x0,x0,x1)   i=256: taps (x510,x511,x511,x510)
//   even j: z = RL2*A[i] + RL0*A[i+1] + RH2*D[i] + RH0*D[i+1],  i=j/2
//   odd  j: z = RL3*A[i] + RL1*A[i+1] + RH3*D[i] + RH1*D[i+1]
//   with D = weight[0] * cD.
// Lane t computes pairs i = 4t..4t+4 and outputs j = 8t..8t+7 of each row.
// Boundary reflections collapse to own-register substitutions at lane 0/63.

#define N 512

typedef float f4v __attribute__((ext_vector_type(4)));

__device__ __forceinline__ void row_compute(
    const f4v va, const f4v vb,
    const float xl0, const float xl1, const float xr0, const float xr1,
    const f4v wv, const float w4,
    f4v& oa, f4v& ob)
{
    constexpr float DL0 = -0.12940952255092145f, DL1 = 0.22414386804185735f,
                    DL2 =  0.836516303737469f,   DL3 = 0.48296291314469025f;
    constexpr float DH0 = -0.48296291314469025f, DH1 = 0.836516303737469f,
                    DH2 = -0.22414386804185735f, DH3 = -0.12940952255092145f;
    constexpr float RL0 =  0.48296291314469025f, RL1 = 0.836516303737469f,
                    RL2 =  0.22414386804185735f, RL3 = -0.12940952255092145f;
    constexpr float RH0 = -0.12940952255092145f, RH1 = -0.22414386804185735f,
                    RH2 =  0.836516303737469f,   RH3 = -0.48296291314469025f;

    // five coefficient pairs: i = 4t+k, k=0..4
    float A0 = DL3*xl0  + DL2*xl1  + DL1*va.x + DL0*va.y;
    float D0 = DH3*xl0  + DH2*xl1  + DH1*va.x + DH0*va.y;
    float A1 = DL3*va.x + DL2*va.y + DL1*va.z + DL0*va.w;
    float D1 = DH3*va.x + DH2*va.y + DH1*va.z + DH0*va.w;
    float A2 = DL3*va.z + DL2*va.w + DL1*vb.x + DL0*vb.y;
    float D2 = DH3*va.z + DH2*va.w + DH1*vb.x + DH0*vb.y;
    float A3 = DL3*vb.x + DL2*vb.y + DL1*vb.z + DL0*vb.w;
    float D3 = DH3*vb.x + DH2*vb.y + DH1*vb.z + DH0*vb.w;
    float A4 = DL3*vb.z + DL2*vb.w + DL1*xr0  + DL0*xr1;
    float D4 = DH3*vb.z + DH2*vb.w + DH1*xr0  + DH0*xr1;

    D0 *= wv.x; D1 *= wv.y; D2 *= wv.z; D3 *= wv.w; D4 *= w4;

    // IDWT: 8 consecutive outputs j = 8t .. 8t+7
    float z0 = RL2*A0 + RL0*A1 + RH2*D0 + RH0*D1;
    float z1 = RL3*A0 + RL1*A1 + RH3*D0 + RH1*D1;
    float z2 = RL2*A1 + RL0*A2 + RH2*D1 + RH0*D2;
    float z3 = RL3*A1 + RL1*A2 + RH3*D1 + RH1*D2;
    float z4 = RL2*A2 + RL0*A3 + RH2*D2 + RH0*D3;
    float z5 = RL3*A2 + RL1*A3 + RH3*D2 + RH1*D3;
    float z6 = RL2*A3 + RL0*A4 + RH2*D3 + RH0*D4;
    float z7 = RL3*A3 + RL1*A4 + RH3*D3 + RH1*D4;

    // leaky_relu(0.01)
    oa.x = fmaxf(z0, 0.f) + 0.01f * fminf(z0, 0.f);
    oa.y = fmaxf(z1, 0.f) + 0.01f * fminf(z1, 0.f);
    oa.z = fmaxf(z2, 0.f) + 0.01f * fminf(z2, 0.f);
    oa.w = fmaxf(z3, 0.f) + 0.01f * fminf(z3, 0.f);
    ob.x = fmaxf(z4, 0.f) + 0.01f * fminf(z4, 0.f);
    ob.y = fmaxf(z5, 0.f) + 0.01f * fminf(z5, 0.f);
    ob.z = fmaxf(z6, 0.f) + 0.01f * fminf(z6, 0.f);
    ob.w = fmaxf(z7, 0.f) + 0.01f * fminf(z7, 0.f);
}

__global__ __launch_bounds__(256) void wavelet_kernel(
    const float* __restrict__ x,
    const float* __restrict__ w,
    float* __restrict__ out,
    int nrows)
{
    const int lane = threadIdx.x & 63;
    const int wid  = threadIdx.x >> 6;

    // Per-lane weights: lane t scales pairs i = 4t .. 4t+4. Fixed across
    // rows -> registers, loaded once. w[4t..4t+3] is 16B-aligned.
    const f4v  wv = *(const f4v*)(w + 4 * lane);
    const float w4 = w[4 * lane + 4];

    const int pairs = nrows >> 1;              // nrows is even (B=65536)
    const int pstep = (int)gridDim.x * 4;

    for (int p = (int)blockIdx.x * 4 + wid; p < pairs; p += pstep) {
        const size_t base0 = ((size_t)p * 2) * N + ((size_t)lane << 3);
        const size_t base1 = base0 + N;

        // issue all 4 loads before any use: 64 B/lane in flight
        f4v va0 = *(const f4v*)(x + base0);
        f4v vb0 = *(const f4v*)(x + base0 + 4);
        f4v va1 = *(const f4v*)(x + base1);
        f4v vb1 = *(const f4v*)(x + base1 + 4);

        // wave-internal halos (lane t-1's e6,e7 / lane t+1's e0,e1)
        float xl00 = __shfl_up(vb0.z, 1);
        float xl01 = __shfl_up(vb0.w, 1);
        float xr00 = __shfl_down(va0.x, 1);
        float xr01 = __shfl_down(va0.y, 1);
        float xl10 = __shfl_up(vb1.z, 1);
        float xl11 = __shfl_up(vb1.w, 1);
        float xr10 = __shfl_down(va1.x, 1);
        float xr11 = __shfl_down(va1.y, 1);

        // symmetric-extension reflections (own-register substitutions)
        if (lane == 0) {
            xl00 = va0.y; xl01 = va0.x;
            xl10 = va1.y; xl11 = va1.x;
        }
        if (lane == 63) {
            xr00 = vb0.w; xr01 = vb0.z;
            xr10 = vb1.w; xr11 = vb1.z;
        }

        f4v oa0, ob0, oa1, ob1;
        row_compute(va0, vb0, xl00, xl01, xr00, xr01, wv, w4, oa0, ob0);
        row_compute(va1, vb1, xl10, xl11, xr10, xr11, wv, w4, oa1, ob1);

        // plain (cached) stores — NT stores capped the write stream in R3
        *(f4v*)(out + base0)     = oa0;
        *(f4v*)(out + base0 + 4) = ob0;
        *(f4v*)(out + base1)     = oa1;
        *(f4v*)(out + base1 + 4) = ob1;
    }
}

extern "C" void kernel_launch(void* const* d_in, const int* in_sizes, int n_in,
                              void* d_out, int out_size, void* d_ws, size_t ws_size,
                              hipStream_t stream) {
    const float* x = (const float*)d_in[0];
    const float* w = (const float*)d_in[1];
    float* out = (float*)d_out;

    const int nrows = in_sizes[0] / N;          // element count / row length
    const int pairs = nrows >> 1;
    int blocks = (pairs + 3) / 4;               // 4 row-pairs per block-iter
    if (blocks > 2048) blocks = 2048;           // 8 blocks/CU, grid-stride rest
    if (blocks < 1) blocks = 1;
    wavelet_kernel<<<blocks, 256, 0, stream>>>(x, w, out, nrows);
}

// Round 4
// 229.401 us; speedup vs baseline: 1.0470x; 1.0130x over previous
//
#include <hip/hip_runtime.h>
#include <stdint.h>

// WaveletLayer fused kernel (fp32): db2 DWT (symmetric ext) -> scale cD by
// weight[0] -> db2 IDWT -> leaky_relu(0.01).
//
// R5 structure (resubmitted after infra failure; no HW data yet): one WAVE =
// FOUR rows of N=512 per loop iteration. Lane t owns 8 consecutive floats of
// each row; all 8 dwordx4 loads are issued before any use -> 128 B/lane in
// flight (R3 stalled at 32 B/lane, VGPR=28; R4 at 64).
// Halo (2 floats each side) via 4 __shfl per row; no LDS, no barrier.
// BOTH streams are NONTEMPORAL: the harness re-poison fill (512 MiB) leaves
// the 256 MiB L3 full of dirty lines; cached streams allocate -> evict ->
// poison write-backs land inside our kernel's window (~+130-260 MB of hidden
// HBM traffic). NT load/store skips L3 allocation entirely. (R3's "NT stores
// are slow" was confounded by its register starvation; the 6.6 TB/s fill
// proves the write path itself is not the cap.)
// Per-lane weights live in registers, reused across the grid-stride loop.
//
// Index algebra (harness-verified R2/R3/R4):
//   cA[i] = DL3*x[2i-2] + DL2*x[2i-1] + DL1*x[2i] + DL0*x[2i+1]  (interior)
//   i=0: taps (x1,x0,x0,x1)   i=256: taps (x510,x511,x511,x510)
//   even j: z = RL2*A[i] + RL0*A[i+1] + RH2*D[i] + RH0*D[i+1],  i=j/2
//   odd  j: z = RL3*A[i] + RL1*A[i+1] + RH3*D[i] + RH1*D[i+1]
//   with D = weight[0] * cD.
// Lane t computes pairs i = 4t..4t+4 and outputs j = 8t..8t+7 of each row.
// Boundary reflections collapse to own-register substitutions at lane 0/63.

#define N 512

typedef float f4v __attribute__((ext_vector_type(4)));

__device__ __forceinline__ void row_compute(
    const f4v va, const f4v vb,
    const float xl0, const float xl1, const float xr0, const float xr1,
    const f4v wv, const float w4,
    f4v& oa, f4v& ob)
{
    constexpr float DL0 = -0.12940952255092145f, DL1 = 0.22414386804185735f,
                    DL2 =  0.836516303737469f,   DL3 = 0.48296291314469025f;
    constexpr float DH0 = -0.48296291314469025f, DH1 = 0.836516303737469f,
                    DH2 = -0.22414386804185735f, DH3 = -0.12940952255092145f;
    constexpr float RL0 =  0.48296291314469025f, RL1 = 0.836516303737469f,
                    RL2 =  0.22414386804185735f, RL3 = -0.12940952255092145f;
    constexpr float RH0 = -0.12940952255092145f, RH1 = -0.22414386804185735f,
                    RH2 =  0.836516303737469f,   RH3 = -0.48296291314469025f;

    // five coefficient pairs: i = 4t+k, k=0..4
    float A0 = DL3*xl0  + DL2*xl1  + DL1*va.x + DL0*va.y;
    float D0 = DH3*xl0  + DH2*xl1  + DH1*va.x + DH0*va.y;
    float A1 = DL3*va.x + DL2*va.y + DL1*va.z + DL0*va.w;
    float D1 = DH3*va.x + DH2*va.y + DH1*va.z + DH0*va.w;
    float A2 = DL3*va.z + DL2*va.w + DL1*vb.x + DL0*vb.y;
    float D2 = DH3*va.z + DH2*va.w + DH1*vb.x + DH0*vb.y;
    float A3 = DL3*vb.x + DL2*vb.y + DL1*vb.z + DL0*vb.w;
    float D3 = DH3*vb.x + DH2*vb.y + DH1*vb.z + DH0*vb.w;
    float A4 = DL3*vb.z + DL2*vb.w + DL1*xr0  + DL0*xr1;
    float D4 = DH3*vb.z + DH2*vb.w + DH1*xr0  + DH0*xr1;

    D0 *= wv.x; D1 *= wv.y; D2 *= wv.z; D3 *= wv.w; D4 *= w4;

    // IDWT: 8 consecutive outputs j = 8t .. 8t+7
    float z0 = RL2*A0 + RL0*A1 + RH2*D0 + RH0*D1;
    float z1 = RL3*A0 + RL1*A1 + RH3*D0 + RH1*D1;
    float z2 = RL2*A1 + RL0*A2 + RH2*D1 + RH0*D2;
    float z3 = RL3*A1 + RL1*A2 + RH3*D1 + RH1*D2;
    float z4 = RL2*A2 + RL0*A3 + RH2*D2 + RH0*D3;
    float z5 = RL3*A2 + RL1*A3 + RH3*D2 + RH1*D3;
    float z6 = RL2*A3 + RL0*A4 + RH2*D3 + RH0*D4;
    float z7 = RL3*A3 + RL1*A4 + RH3*D3 + RH1*D4;

    // leaky_relu(0.01)
    oa.x = fmaxf(z0, 0.f) + 0.01f * fminf(z0, 0.f);
    oa.y = fmaxf(z1, 0.f) + 0.01f * fminf(z1, 0.f);
    oa.z = fmaxf(z2, 0.f) + 0.01f * fminf(z2, 0.f);
    oa.w = fmaxf(z3, 0.f) + 0.01f * fminf(z3, 0.f);
    ob.x = fmaxf(z4, 0.f) + 0.01f * fminf(z4, 0.f);
    ob.y = fmaxf(z5, 0.f) + 0.01f * fminf(z5, 0.f);
    ob.z = fmaxf(z6, 0.f) + 0.01f * fminf(z6, 0.f);
    ob.w = fmaxf(z7, 0.f) + 0.01f * fminf(z7, 0.f);
}

__device__ __forceinline__ void halo(
    const f4v va, const f4v vb, const int lane,
    float& xl0, float& xl1, float& xr0, float& xr1)
{
    // wave-internal halo: lane t-1's e6,e7 and lane t+1's e0,e1
    xl0 = __shfl_up(vb.z, 1);
    xl1 = __shfl_up(vb.w, 1);
    xr0 = __shfl_down(va.x, 1);
    xr1 = __shfl_down(va.y, 1);
    // symmetric-extension reflections (own-register substitutions)
    if (lane == 0)  { xl0 = va.y; xl1 = va.x; }
    if (lane == 63) { xr0 = vb.w; xr1 = vb.z; }
}

__global__ __launch_bounds__(256) void wavelet_kernel(
    const float* __restrict__ x,
    const float* __restrict__ w,
    float* __restrict__ out,
    int nrows)
{
    const int lane = threadIdx.x & 63;
    const int wid  = threadIdx.x >> 6;

    // Per-lane weights: lane t scales pairs i = 4t .. 4t+4. Fixed across
    // rows -> registers, loaded once (cached loads; reused).
    const f4v  wv = *(const f4v*)(w + 4 * lane);
    const float w4 = w[4 * lane + 4];

    const int quads = nrows >> 2;              // nrows % 4 == 0 (B=65536)
    const int qstep = (int)gridDim.x * 4;

    for (int q = (int)blockIdx.x * 4 + wid; q < quads; q += qstep) {
        const size_t base0 = ((size_t)q * 4) * N + ((size_t)lane << 3);
        const size_t base1 = base0 + N;
        const size_t base2 = base0 + 2 * N;
        const size_t base3 = base0 + 3 * N;

        // issue all 8 loads before any use: 128 B/lane in flight, NT (no L3
        // allocation -> no dirty-poison evictions in our window)
        f4v va0 = __builtin_nontemporal_load((const f4v*)(x + base0));
        f4v vb0 = __builtin_nontemporal_load((const f4v*)(x + base0 + 4));
        f4v va1 = __builtin_nontemporal_load((const f4v*)(x + base1));
        f4v vb1 = __builtin_nontemporal_load((const f4v*)(x + base1 + 4));
        f4v va2 = __builtin_nontemporal_load((const f4v*)(x + base2));
        f4v vb2 = __builtin_nontemporal_load((const f4v*)(x + base2 + 4));
        f4v va3 = __builtin_nontemporal_load((const f4v*)(x + base3));
        f4v vb3 = __builtin_nontemporal_load((const f4v*)(x + base3 + 4));

        float xl0, xl1, xr0, xr1;
        f4v oa, ob;

        halo(va0, vb0, lane, xl0, xl1, xr0, xr1);
        row_compute(va0, vb0, xl0, xl1, xr0, xr1, wv, w4, oa, ob);
        __builtin_nontemporal_store(oa, (f4v*)(out + base0));
        __builtin_nontemporal_store(ob, (f4v*)(out + base0 + 4));

        halo(va1, vb1, lane, xl0, xl1, xr0, xr1);
        row_compute(va1, vb1, xl0, xl1, xr0, xr1, wv, w4, oa, ob);
        __builtin_nontemporal_store(oa, (f4v*)(out + base1));
        __builtin_nontemporal_store(ob, (f4v*)(out + base1 + 4));

        halo(va2, vb2, lane, xl0, xl1, xr0, xr1);
        row_compute(va2, vb2, xl0, xl1, xr0, xr1, wv, w4, oa, ob);
        __builtin_nontemporal_store(oa, (f4v*)(out + base2));
        __builtin_nontemporal_store(ob, (f4v*)(out + base2 + 4));

        halo(va3, vb3, lane, xl0, xl1, xr0, xr1);
        row_compute(va3, vb3, xl0, xl1, xr0, xr1, wv, w4, oa, ob);
        __builtin_nontemporal_store(oa, (f4v*)(out + base3));
        __builtin_nontemporal_store(ob, (f4v*)(out + base3 + 4));
    }
}

extern "C" void kernel_launch(void* const* d_in, const int* in_sizes, int n_in,
                              void* d_out, int out_size, void* d_ws, size_t ws_size,
                              hipStream_t stream) {
    const float* x = (const float*)d_in[0];
    const float* w = (const float*)d_in[1];
    float* out = (float*)d_out;

    const int nrows = in_sizes[0] / N;          // element count / row length
    const int quads = nrows >> 2;
    int blocks = (quads + 3) / 4;               // 4 row-quads per block-iter
    if (blocks > 2048) blocks = 2048;           // grid-stride the rest
    if (blocks < 1) blocks = 1;
    wavelet_kernel<<<blocks, 256, 0, stream>>>(x, w, out, nrows);
}